// Round 1
// baseline (118.084 us; speedup 1.0000x reference)
//
#include <hip/hip_runtime.h>
#include <math.h>

#define Bb 2
#define Tt 256
#define Ee 512
#define Hh 8
#define Dd 64
#define E3 1536

// C[M][N] = A[M][K] @ W[K][N] + bias[N]; M,N,K multiples of 64/16
__global__ __launch_bounds__(256) void gemm_bias_kernel(
    const float* __restrict__ A, const float* __restrict__ W,
    const float* __restrict__ bias, float* __restrict__ C,
    int M, int N, int K)
{
    __shared__ float As[64][20];   // [row][k], pad 20 keeps float4 alignment, no conflicts
    __shared__ float Bs[16][64];   // [k][col]
    const int tid = threadIdx.x;
    const int tx = tid & 15, ty = tid >> 4;
    const int n0 = blockIdx.x * 64, m0 = blockIdx.y * 64;
    const int lr = tid >> 2, lk = (tid & 3) << 2;   // A-tile load: row, k-offset
    const int bk = tid >> 4, bc = (tid & 15) << 2;  // B-tile load: k, col
    float acc[4][4] = {};
    for (int k0 = 0; k0 < K; k0 += 16) {
        const float4 av = *(const float4*)&A[(size_t)(m0 + lr) * K + k0 + lk];
        const float4 bv = *(const float4*)&W[(size_t)(k0 + bk) * N + n0 + bc];
        __syncthreads();
        *(float4*)&As[lr][lk] = av;
        *(float4*)&Bs[bk][bc] = bv;
        __syncthreads();
        #pragma unroll
        for (int k4 = 0; k4 < 4; ++k4) {
            float a_[4][4], b_[4][4];
            #pragma unroll
            for (int i = 0; i < 4; ++i)
                *(float4*)a_[i] = *(const float4*)&As[ty * 4 + i][k4 * 4];
            #pragma unroll
            for (int jk = 0; jk < 4; ++jk)
                *(float4*)b_[jk] = *(const float4*)&Bs[k4 * 4 + jk][tx * 4];
            #pragma unroll
            for (int jk = 0; jk < 4; ++jk)
                #pragma unroll
                for (int i = 0; i < 4; ++i)
                    #pragma unroll
                    for (int j = 0; j < 4; ++j)
                        acc[i][j] = fmaf(a_[i][jk], b_[jk][j], acc[i][j]);
        }
    }
    const float4 bs4 = *(const float4*)&bias[n0 + tx * 4];
    #pragma unroll
    for (int i = 0; i < 4; ++i) {
        float4 o;
        o.x = acc[i][0] + bs4.x;
        o.y = acc[i][1] + bs4.y;
        o.z = acc[i][2] + bs4.z;
        o.w = acc[i][3] + bs4.w;
        *(float4*)&C[(size_t)(m0 + ty * 4 + i) * N + n0 + tx * 4] = o;
    }
}

// One block per (b, pair of t rows). 256 threads. Thread s computes scores for
// both t rows and all 8 heads, then block does softmax + attn_weights + PV.
__global__ __launch_bounds__(256) void attn_kernel(
    const float* __restrict__ qkv,     // (B*T, 1536): [q|k|v]
    const float* __restrict__ mask,    // (B, T, T, 32, 2)
    const float* __restrict__ pad,     // (B, T)
    float* __restrict__ o_attn,        // (B*T, 512)
    float* __restrict__ attn_w)        // (B*T, 256)
{
    __shared__ float q_s[2][Ee];
    __shared__ float sc[2][Hh][Tt];
    __shared__ float rrs[16];          // reciprocal softmax sums, row = tt*8+h
    const int tid = threadIdx.x;
    const int b  = blockIdx.x >> 7;
    const int t0 = (blockIdx.x & 127) * 2;

    #pragma unroll
    for (int i = 0; i < 4; ++i) {
        const int e = tid + i * 256;
        q_s[e >> 9][e & 511] = qkv[(size_t)(b * Tt + t0 + (e >> 9)) * E3 + (e & 511)];
    }
    __syncthreads();

    const int s = tid;
    const float padv = pad[b * Tt + s];
    const float* kb  = qkv + (size_t)(b * Tt + s) * E3 + Ee;
    const float* mb0 = mask + (size_t)((b * Tt + t0) * Tt + s) * Dd;
    const float* mb1 = mb0 + (size_t)Tt * Dd;

    float acc[2][Hh];
    #pragma unroll
    for (int tt = 0; tt < 2; ++tt)
        #pragma unroll
        for (int h = 0; h < Hh; ++h) acc[tt][h] = 0.f;

    #pragma unroll 4
    for (int pc = 0; pc < 16; ++pc) {           // 2 complex pairs per float4
        const float4 m0 = *(const float4*)(mb0 + pc * 4);
        const float4 m1 = *(const float4*)(mb1 + pc * 4);
        #pragma unroll
        for (int h = 0; h < Hh; ++h) {
            const float4 kk = *(const float4*)(kb + h * 64 + pc * 4);
            const float4 q0 = *(const float4*)&q_s[0][h * 64 + pc * 4];
            const float4 q1 = *(const float4*)&q_s[1][h * 64 + pc * 4];
            acc[0][h] += kk.x * (q0.x * m0.x + q0.y * m0.y)
                       + kk.y * (q0.y * m0.x - q0.x * m0.y)
                       + kk.z * (q0.z * m0.z + q0.w * m0.w)
                       + kk.w * (q0.w * m0.z - q0.z * m0.w);
            acc[1][h] += kk.x * (q1.x * m1.x + q1.y * m1.y)
                       + kk.y * (q1.y * m1.x - q1.x * m1.y)
                       + kk.z * (q1.z * m1.z + q1.w * m1.w)
                       + kk.w * (q1.w * m1.z - q1.z * m1.w);
        }
    }
    const float scale = 0.125f;  // 1/sqrt(64)
    #pragma unroll
    for (int tt = 0; tt < 2; ++tt)
        #pragma unroll
        for (int h = 0; h < Hh; ++h)
            sc[tt][h][s] = acc[tt][h] * scale + padv;
    __syncthreads();

    // softmax: 16 rows (tt,h), 16 threads per row
    {
        const int row = tid >> 4, l16 = tid & 15;
        float* scrow = &sc[0][0][0] + row * Tt;
        float mx = -INFINITY;
        #pragma unroll
        for (int i = 0; i < 16; ++i) mx = fmaxf(mx, scrow[l16 + i * 16]);
        #pragma unroll
        for (int d = 8; d >= 1; d >>= 1) mx = fmaxf(mx, __shfl_xor(mx, d));
        float sum = 0.f;
        #pragma unroll
        for (int i = 0; i < 16; ++i) {
            const float e = __expf(scrow[l16 + i * 16] - mx);
            scrow[l16 + i * 16] = e;
            sum += e;
        }
        #pragma unroll
        for (int d = 8; d >= 1; d >>= 1) sum += __shfl_xor(sum, d);
        if (l16 == 0) rrs[row] = 1.f / sum;
    }
    __syncthreads();

    // attn_weights = mean over heads of normalized probs
    {
        float aw0 = 0.f, aw1 = 0.f;
        #pragma unroll
        for (int h = 0; h < Hh; ++h) {
            aw0 += sc[0][h][s] * rrs[h];
            aw1 += sc[1][h][s] * rrs[8 + h];
        }
        attn_w[(size_t)(b * Tt + t0) * Tt + s]     = aw0 * (1.f / Hh);
        attn_w[(size_t)(b * Tt + t0 + 1) * Tt + s] = aw1 * (1.f / Hh);
    }

    // PV: thread (hb, d) accumulates heads hb and hb+4 for both t rows
    {
        const int d = tid & 63, hb = tid >> 6;
        const float* vb = qkv + (size_t)b * Tt * E3 + 2 * Ee;
        float o00 = 0.f, o01 = 0.f, o10 = 0.f, o11 = 0.f;
        #pragma unroll 4
        for (int s2 = 0; s2 < Tt; ++s2) {
            const float v0 = vb[(size_t)s2 * E3 + hb * 64 + d];
            const float v1 = vb[(size_t)s2 * E3 + (hb + 4) * 64 + d];
            o00 += sc[0][hb][s2]     * v0;
            o01 += sc[0][hb + 4][s2] * v1;
            o10 += sc[1][hb][s2]     * v0;
            o11 += sc[1][hb + 4][s2] * v1;
        }
        float* ob0 = o_attn + (size_t)(b * Tt + t0) * Ee;
        float* ob1 = ob0 + Ee;
        ob0[hb * 64 + d]       = o00 * rrs[hb];
        ob0[(hb + 4) * 64 + d] = o01 * rrs[hb + 4];
        ob1[hb * 64 + d]       = o10 * rrs[8 + hb];
        ob1[(hb + 4) * 64 + d] = o11 * rrs[8 + hb + 4];
    }
}

extern "C" void kernel_launch(void* const* d_in, const int* in_sizes, int n_in,
                              void* d_out, int out_size, void* d_ws, size_t ws_size,
                              hipStream_t stream) {
    const float* x    = (const float*)d_in[0];
    const float* mask = (const float*)d_in[1];
    const float* pad  = (const float*)d_in[2];
    const float* Wqkv = (const float*)d_in[3];
    const float* bqkv = (const float*)d_in[4];
    const float* Wo   = (const float*)d_in[5];
    const float* bo   = (const float*)d_in[6];

    float* out    = (float*)d_out;               // o (B*T*E) then attn_w (B*T*T)
    float* qkv    = (float*)d_ws;                // B*T*3E = 786432 floats
    float* o_attn = qkv + (size_t)Bb * Tt * E3;  // B*T*E  = 262144 floats

    // qkv = x @ Wqkv + bqkv
    gemm_bias_kernel<<<dim3(E3 / 64, (Bb * Tt) / 64), 256, 0, stream>>>(
        x, Wqkv, bqkv, qkv, Bb * Tt, E3, Ee);

    // fused rotary scores + softmax + attn_weights + PV
    attn_kernel<<<dim3((Bb * Tt) / 2), 256, 0, stream>>>(
        qkv, mask, pad, o_attn, out + (size_t)Bb * Tt * Ee);

    // out = o_attn @ Wo + bo
    gemm_bias_kernel<<<dim3(Ee / 64, (Bb * Tt) / 64), 256, 0, stream>>>(
        o_attn, Wo, bo, out, Bb * Tt, Ee, Ee);
}

// Round 3
// 87.451 us; speedup vs baseline: 1.3503x; 1.3503x over previous
//
#include <hip/hip_runtime.h>
#include <math.h>

#define Bb 2
#define Tt 256
#define Ee 512
#define Hh 8
#define Dd 64
#define E3 1536

typedef float vfloat4 __attribute__((ext_vector_type(4)));

__device__ inline float4 ntload4(const float* p) {
    vfloat4 v = __builtin_nontemporal_load((const vfloat4*)p);
    return make_float4(v.x, v.y, v.z, v.w);
}

// C[M][N] = A[M][K] @ W[K][N] + bias[N]; tile 32x64, BK=16, 256 threads, 2x4/thread
__global__ __launch_bounds__(256) void gemm_bias_kernel(
    const float* __restrict__ A, const float* __restrict__ W,
    const float* __restrict__ bias, float* __restrict__ C,
    int M, int N, int K)
{
    __shared__ float As[32][18];   // stride 18 (even, conflict-free)
    __shared__ float Bs[16][68];   // stride 68 (16B-aligned rows, conflict-free)
    const int tid = threadIdx.x;
    const int tx = tid & 15;               // col group: cols tx*4..+3
    const int ty = tid >> 4;               // 0..15: rows ty*2, ty*2+1
    const int n0 = blockIdx.x * 64, m0 = blockIdx.y * 32;
    const int lr = tid >> 3, lk = (tid & 7) * 2;   // A tile load 32x16
    const int bk = tid >> 4, bc = (tid & 15) * 4;  // B tile load 16x64
    float acc[2][4] = {};
    for (int k0 = 0; k0 < K; k0 += 16) {
        const float2 av = *(const float2*)&A[(size_t)(m0 + lr) * K + k0 + lk];
        const float4 bv = *(const float4*)&W[(size_t)(k0 + bk) * N + n0 + bc];
        __syncthreads();
        *(float2*)&As[lr][lk] = av;
        *(float4*)&Bs[bk][bc] = bv;
        __syncthreads();
        #pragma unroll
        for (int k = 0; k < 16; ++k) {
            const float a0 = As[ty * 2][k];
            const float a1 = As[ty * 2 + 1][k];
            const float4 b4 = *(const float4*)&Bs[k][tx * 4];
            acc[0][0] = fmaf(a0, b4.x, acc[0][0]);
            acc[0][1] = fmaf(a0, b4.y, acc[0][1]);
            acc[0][2] = fmaf(a0, b4.z, acc[0][2]);
            acc[0][3] = fmaf(a0, b4.w, acc[0][3]);
            acc[1][0] = fmaf(a1, b4.x, acc[1][0]);
            acc[1][1] = fmaf(a1, b4.y, acc[1][1]);
            acc[1][2] = fmaf(a1, b4.z, acc[1][2]);
            acc[1][3] = fmaf(a1, b4.w, acc[1][3]);
        }
    }
    const float4 bs4 = *(const float4*)&bias[n0 + tx * 4];
    #pragma unroll
    for (int r = 0; r < 2; ++r) {
        float4 o;
        o.x = acc[r][0] + bs4.x;
        o.y = acc[r][1] + bs4.y;
        o.z = acc[r][2] + bs4.z;
        o.w = acc[r][3] + bs4.w;
        *(float4*)&C[(size_t)(m0 + ty * 2 + r) * N + n0 + tx * 4] = o;
    }
}

// Block = (b, t-pair). 512 threads / 8 waves. Lane = (si in 8 s-rows, dq in 8 d-octets).
__global__ __launch_bounds__(512, 2) void attn_kernel(
    const float* __restrict__ qkv,     // (B*T, 1536): [q|k|v]
    const float* __restrict__ mask,    // (B, T, T, 32, 2) = (..., 64 floats)
    const float* __restrict__ pad,     // (B, T)
    float* __restrict__ o_attn,        // (B*T, 512)
    float* __restrict__ attn_w)        // (B*T, 256)
{
    __shared__ float q_s[2][Ee];       // 4 KB
    __shared__ float sc[2][Hh][Tt];    // 16 KB
    __shared__ float rrs[16];          // reciprocal softmax sums, row = tt*8+h
    const int tid  = threadIdx.x;
    const int lane = tid & 63;
    const int wv   = tid >> 6;         // 0..7
    const int si   = lane >> 3;        // 0..7
    const int dq   = lane & 7;         // 0..7 -> d = dq*8..dq*8+7
    const int b    = blockIdx.x >> 7;
    const int t0   = (blockIdx.x & 127) * 2;

    // stage q rows (t0, t0+1) into LDS: 1024 floats, float2 per thread
    {
        const int e = tid * 2;
        const int t = e >> 9, off = e & 511;
        *(float2*)&q_s[t][off] =
            *(const float2*)&qkv[(size_t)(b * Tt + t0 + t) * E3 + off];
    }
    __syncthreads();

    const float scale = 0.125f;  // 1/sqrt(64)

    // ---- scores: wave handles 4 chunks of 8 s-rows ----
    for (int c = 0; c < 4; ++c) {
        const int s = (wv * 4 + c) * 8 + si;
        const float* mrow0 = mask + ((size_t)((b * Tt + t0) * Tt + s)) * Dd + dq * 8;
        const float* mrow1 = mrow0 + (size_t)Tt * Dd;
        const float4 ma0 = ntload4(mrow0);
        const float4 mb0 = ntload4(mrow0 + 4);
        const float4 ma1 = ntload4(mrow1);
        const float4 mb1 = ntload4(mrow1 + 4);
        const float* krow = qkv + (size_t)(b * Tt + s) * E3 + Ee + dq * 8;
        const float padv = pad[b * Tt + s];
        #pragma unroll
        for (int h = 0; h < Hh; ++h) {
            const float4 ka = *(const float4*)(krow + h * 64);
            const float4 kb = *(const float4*)(krow + h * 64 + 4);
            const float4 qa0 = *(const float4*)&q_s[0][h * 64 + dq * 8];
            const float4 qb0 = *(const float4*)&q_s[0][h * 64 + dq * 8 + 4];
            const float4 qa1 = *(const float4*)&q_s[1][h * 64 + dq * 8];
            const float4 qb1 = *(const float4*)&q_s[1][h * 64 + dq * 8 + 4];
            // t0
            float u0 = qa0.x * ka.x + qa0.y * ka.y;
            float w0 = qa0.y * ka.x - qa0.x * ka.y;
            float u1 = qa0.z * ka.z + qa0.w * ka.w;
            float w1 = qa0.w * ka.z - qa0.z * ka.w;
            float u2 = qb0.x * kb.x + qb0.y * kb.y;
            float w2 = qb0.y * kb.x - qb0.x * kb.y;
            float u3 = qb0.z * kb.z + qb0.w * kb.w;
            float w3 = qb0.w * kb.z - qb0.z * kb.w;
            float v0 = u0 * ma0.x + w0 * ma0.y + u1 * ma0.z + w1 * ma0.w
                     + u2 * mb0.x + w2 * mb0.y + u3 * mb0.z + w3 * mb0.w;
            // t1
            float s0 = qa1.x * ka.x + qa1.y * ka.y;
            float r0 = qa1.y * ka.x - qa1.x * ka.y;
            float s1 = qa1.z * ka.z + qa1.w * ka.w;
            float r1 = qa1.w * ka.z - qa1.z * ka.w;
            float s2 = qb1.x * kb.x + qb1.y * kb.y;
            float r2 = qb1.y * kb.x - qb1.x * kb.y;
            float s3 = qb1.z * kb.z + qb1.w * kb.w;
            float r3 = qb1.w * kb.z - qb1.z * kb.w;
            float v1 = s0 * ma1.x + r0 * ma1.y + s1 * ma1.z + r1 * ma1.w
                     + s2 * mb1.x + r2 * mb1.y + s3 * mb1.z + r3 * mb1.w;
            // reduce over dq (8 lanes)
            v0 += __shfl_xor(v0, 1); v0 += __shfl_xor(v0, 2); v0 += __shfl_xor(v0, 4);
            v1 += __shfl_xor(v1, 1); v1 += __shfl_xor(v1, 2); v1 += __shfl_xor(v1, 4);
            if (dq == 0) {
                sc[0][h][s] = v0 * scale + padv;
                sc[1][h][s] = v1 * scale + padv;
            }
        }
    }
    __syncthreads();

    // ---- softmax: 16 rows (t,h); wave handles rows wv*2, wv*2+1 ----
    #pragma unroll
    for (int r = 0; r < 2; ++r) {
        const int row = wv * 2 + r;
        float* pr = &sc[0][0][0] + row * Tt;
        float4 xv = *(const float4*)&pr[lane * 4];
        float mx = fmaxf(fmaxf(xv.x, xv.y), fmaxf(xv.z, xv.w));
        #pragma unroll
        for (int dlt = 32; dlt >= 1; dlt >>= 1) mx = fmaxf(mx, __shfl_xor(mx, dlt));
        float4 ev;
        ev.x = __expf(xv.x - mx);
        ev.y = __expf(xv.y - mx);
        ev.z = __expf(xv.z - mx);
        ev.w = __expf(xv.w - mx);
        float sum = (ev.x + ev.y) + (ev.z + ev.w);
        #pragma unroll
        for (int dlt = 32; dlt >= 1; dlt >>= 1) sum += __shfl_xor(sum, dlt);
        *(float4*)&pr[lane * 4] = ev;
        if (lane == 0) rrs[row] = 1.0f / sum;
    }
    __syncthreads();

    // ---- attn_weights: thread (tt, s2) ----
    {
        const int tt = tid >> 8, s2 = tid & 255;
        float aw = 0.f;
        #pragma unroll
        for (int h = 0; h < Hh; ++h) aw += sc[tt][h][s2] * rrs[tt * 8 + h];
        attn_w[(size_t)(b * Tt + t0 + tt) * Tt + s2] = aw * 0.125f;
    }

    // ---- PV: thread (h, d), both t rows share v loads ----
    {
        const int h = tid >> 6, d = tid & 63;
        const float r0 = rrs[h], r1 = rrs[8 + h];
        const float* vb = qkv + (size_t)b * Tt * E3 + 2 * Ee + h * 64 + d;
        float o0 = 0.f, o1 = 0.f;
        for (int s2 = 0; s2 < Tt; s2 += 4) {
            const float4 p0 = *(const float4*)&sc[0][h][s2];
            const float4 p1 = *(const float4*)&sc[1][h][s2];
            float vv;
            vv = vb[(size_t)(s2 + 0) * E3]; o0 = fmaf(p0.x, vv, o0); o1 = fmaf(p1.x, vv, o1);
            vv = vb[(size_t)(s2 + 1) * E3]; o0 = fmaf(p0.y, vv, o0); o1 = fmaf(p1.y, vv, o1);
            vv = vb[(size_t)(s2 + 2) * E3]; o0 = fmaf(p0.z, vv, o0); o1 = fmaf(p1.z, vv, o1);
            vv = vb[(size_t)(s2 + 3) * E3]; o0 = fmaf(p0.w, vv, o0); o1 = fmaf(p1.w, vv, o1);
        }
        o_attn[(size_t)(b * Tt + t0) * Ee + tid]     = o0 * r0;
        o_attn[(size_t)(b * Tt + t0 + 1) * Ee + tid] = o1 * r1;
    }
}

extern "C" void kernel_launch(void* const* d_in, const int* in_sizes, int n_in,
                              void* d_out, int out_size, void* d_ws, size_t ws_size,
                              hipStream_t stream) {
    const float* x    = (const float*)d_in[0];
    const float* mask = (const float*)d_in[1];
    const float* pad  = (const float*)d_in[2];
    const float* Wqkv = (const float*)d_in[3];
    const float* bqkv = (const float*)d_in[4];
    const float* Wo   = (const float*)d_in[5];
    const float* bo   = (const float*)d_in[6];

    float* out    = (float*)d_out;               // o (B*T*E) then attn_w (B*T*T)
    float* qkv    = (float*)d_ws;                // B*T*3E = 786432 floats
    float* o_attn = qkv + (size_t)Bb * Tt * E3;  // B*T*E  = 262144 floats

    // qkv = x @ Wqkv + bqkv   (grid 24 x 16 = 384 blocks)
    gemm_bias_kernel<<<dim3(E3 / 64, (Bb * Tt) / 32), 256, 0, stream>>>(
        x, Wqkv, bqkv, qkv, Bb * Tt, E3, Ee);

    // fused rotary scores + softmax + attn_weights + PV  (256 blocks x 512 thr)
    attn_kernel<<<dim3(Bb * (Tt / 2)), 512, 0, stream>>>(
        qkv, mask, pad, o_attn, out + (size_t)Bb * Tt * Ee);

    // out = o_attn @ Wo + bo  (grid 8 x 16 = 128 blocks)
    gemm_bias_kernel<<<dim3(Ee / 64, (Bb * Tt) / 32), 256, 0, stream>>>(
        o_attn, Wo, bo, out, Bb * Tt, Ee, Ee);
}